// Round 6
// baseline (607.393 us; speedup 1.0000x reference)
//
#include <hip/hip_runtime.h>
#include <hip/hip_bf16.h>

#define N_NODES 50000
#define N_EDGES 600000
#define HID 128

typedef __attribute__((ext_vector_type(8))) short s8v;            // 8 bf16 = 4 VGPR
typedef __attribute__((ext_vector_type(8))) unsigned short u8v;   // 8 ushort
typedef __attribute__((ext_vector_type(4))) float f4v;            // MFMA acc

// ---------------- bf16 helpers ----------------
__device__ __forceinline__ unsigned short f2bf(float x) {
    unsigned u = __float_as_uint(x);
    unsigned r = u + 0x7FFFu + ((u >> 16) & 1u);   // RNE
    return (unsigned short)(r >> 16);
}
__device__ __forceinline__ float bf2f(unsigned short u) {
    return __uint_as_float((unsigned)u << 16);
}
__device__ __forceinline__ void split_bf(float x, unsigned short& hi, unsigned short& lo) {
    hi = f2bf(x);
    lo = f2bf(x - bf2f(hi));
}

// ---------------- edge dtype detection ----------------
__global__ void detect_mode(const void* __restrict__ edges, int* __restrict__ flag) {
    __shared__ int any;
    if (threadIdx.x == 0) any = 0;
    __syncthreads();
    const int* p = (const int*)edges;
    if (p[2 * threadIdx.x + 1] != 0) any = 1;  // benign race
    __syncthreads();
    if (threadIdx.x == 0) *flag = (any == 0) ? 1 : 0;  // 1 => int64
}

__device__ __forceinline__ int edge_at(const void* edges, int mode64, long long idx) {
    return mode64 ? (int)((const long long*)edges)[idx] : ((const int*)edges)[idx];
}

// ---------------- CSR build ----------------
__global__ void count_deg(const void* __restrict__ edges, const int* __restrict__ flag,
                          int* __restrict__ deg) {
    int e = blockIdx.x * 256 + threadIdx.x;
    if (e >= N_EDGES) return;
    int m = *flag;
    int d = edge_at(edges, m, (long long)N_EDGES + e);
    if ((unsigned)d < (unsigned)N_NODES) atomicAdd(&deg[d], 1);
}

__global__ void scan_block(const int* __restrict__ deg, int* __restrict__ offs,
                           int* __restrict__ blocksum) {
    __shared__ int sm[256];
    int i = blockIdx.x * 256 + threadIdx.x;
    int v = (i < N_NODES) ? deg[i] : 0;
    sm[threadIdx.x] = v;
    __syncthreads();
    #pragma unroll
    for (int s = 1; s < 256; s <<= 1) {
        int t = (threadIdx.x >= (unsigned)s) ? sm[threadIdx.x - s] : 0;
        __syncthreads();
        sm[threadIdx.x] += t;
        __syncthreads();
    }
    if (i < N_NODES) offs[i] = sm[threadIdx.x] - v;
    if (threadIdx.x == 255) blocksum[blockIdx.x] = sm[255];
}

__global__ void scan_top(int* __restrict__ blocksum, int nblocks) {
    __shared__ int sm[256];
    int v = ((int)threadIdx.x < nblocks) ? blocksum[threadIdx.x] : 0;
    sm[threadIdx.x] = v;
    __syncthreads();
    #pragma unroll
    for (int s = 1; s < 256; s <<= 1) {
        int t = (threadIdx.x >= (unsigned)s) ? sm[threadIdx.x - s] : 0;
        __syncthreads();
        sm[threadIdx.x] += t;
        __syncthreads();
    }
    if ((int)threadIdx.x < nblocks) blocksum[threadIdx.x] = sm[threadIdx.x] - v;
    if (threadIdx.x == 255) blocksum[nblocks] = sm[255];
}

__global__ void scan_add(int* __restrict__ offs, int* __restrict__ cursor,
                         const int* __restrict__ blocksum, int nblocks) {
    int i = blockIdx.x * 256 + threadIdx.x;
    if (i < N_NODES) {
        int o = offs[i] + blocksum[blockIdx.x];
        offs[i] = o;
        cursor[i] = o;
    }
    if (i == 0) offs[N_NODES] = blocksum[nblocks];
}

__global__ void fill_csr(const void* __restrict__ edges, const int* __restrict__ flag,
                         int* __restrict__ cursor, int* __restrict__ csr) {
    int e = blockIdx.x * 256 + threadIdx.x;
    if (e >= N_EDGES) return;
    int m = *flag;
    int d = edge_at(edges, m, (long long)N_EDGES + e);
    int s = edge_at(edges, m, (long long)e);
    if ((unsigned)d >= (unsigned)N_NODES || (unsigned)s >= (unsigned)N_NODES) return;
    int pos = atomicAdd(&cursor[d], 1);
    csr[pos] = s;
}

// ---------------- prep: weight split + x split (merged) ----------------
__global__ void prep(const float* __restrict__ m0, const float* __restrict__ m1,
                     const float* __restrict__ m2, const float* __restrict__ m3,
                     const float* __restrict__ m4, const float* __restrict__ m5,
                     unsigned short* __restrict__ whi, unsigned short* __restrict__ wlo,
                     const float* __restrict__ x, unsigned short* __restrict__ xhi,
                     unsigned short* __restrict__ xlo, int n4) {
    int i = blockIdx.x * 256 + threadIdx.x;
    if (i < 6 * HID * HID) {
        int mat = i >> 14, off = i & 16383;
        const float* src = mat == 0 ? m0 : mat == 1 ? m1 : mat == 2 ? m2
                         : mat == 3 ? m3 : mat == 4 ? m4 : m5;
        unsigned short h, l;
        split_bf(src[off], h, l);
        whi[i] = h; wlo[i] = l;
    }
    if (i < n4) {
        float4 v = ((const float4*)x)[i];
        ushort4 h, l;
        split_bf(v.x, h.x, l.x);
        split_bf(v.y, h.y, l.y);
        split_bf(v.z, h.z, l.z);
        split_bf(v.w, h.w, l.w);
        ((ushort4*)xhi)[i] = h;
        ((ushort4*)xlo)[i] = l;
    }
}

// ---------------- fused SAGE layer: aggregate (-> LDS) + MFMA GEMM ----------
// out[i,:] = mean[i,:] @ Wl^T + h[i,:] @ Wr^T + b  via 16x16x32 bf16 MFMA,
// 3-term split: Ah*Bh + Al*Bh + Ah*Bl (err ~2^-18).
// Block = 256 thr (4 waves), 64 output rows.
//   Phase A: mean-gather for the block's 64 rows straight into LDS (hi/lo)
//            -- the mean NEVER touches global memory (saves ~150 MB/call).
//   Phase B: 64x128 GEMM; wave -> 32x64 quadrant (2x4 MFMA tiles).
//            B staged per 32-k panel in LDS (stride 40 shorts, 16B-aligned);
//            phase-1 A (h rows) register-prefetched one panel ahead.
// LDS: 2*(64*136) + 2*(128*40) shorts = 54 KB -> 2 blocks/CU; gather stays
// BW-saturated per Little's law (8 waves x 8 x 1KB in flight >> per-CU share).
template <int RELU, int FINAL>
__global__ __launch_bounds__(256) void sage_layer(
    const unsigned short* __restrict__ Hhi, const unsigned short* __restrict__ Hlo,
    const int* __restrict__ offs, const int* __restrict__ csr,
    const unsigned short* __restrict__ Whi, const unsigned short* __restrict__ Wlo,
    const float* __restrict__ bias,
    unsigned short* __restrict__ ohi, unsigned short* __restrict__ olo,
    float* __restrict__ of32) {
    __shared__ short MhS[64 * 136];
    __shared__ short MlS[64 * 136];
    __shared__ short BhS[128 * 40];
    __shared__ short BlS[128 * 40];
    const int tid = threadIdx.x;
    const int rb = blockIdx.x * 64;

    // ---------- Phase A: aggregation into LDS ----------
    {
        const int sub = tid & 15;          // 16B segment within 256B row
        const int grp = tid >> 4;          // 16 groups; 4 nodes each (serial)
        #pragma unroll 1
        for (int rep = 0; rep < 4; ++rep) {
            const int nloc = rep * 16 + grp;
            const int node = rb + nloc;
            float a[8] = {0.f, 0.f, 0.f, 0.f, 0.f, 0.f, 0.f, 0.f};
            float inv = 1.0f;
            if (node < N_NODES) {
                const int beg = offs[node], end = offs[node + 1];
                if (end > beg) inv = 1.0f / (float)(end - beg);
                int p = beg;
                for (; p + 8 <= end; p += 8) {
                    int s0 = csr[p],     s1 = csr[p + 1], s2 = csr[p + 2], s3 = csr[p + 3];
                    int s4 = csr[p + 4], s5 = csr[p + 5], s6 = csr[p + 6], s7 = csr[p + 7];
                    u8v v0 = *(const u8v*)(Hhi + (size_t)s0 * HID + sub * 8);
                    u8v v1 = *(const u8v*)(Hhi + (size_t)s1 * HID + sub * 8);
                    u8v v2 = *(const u8v*)(Hhi + (size_t)s2 * HID + sub * 8);
                    u8v v3 = *(const u8v*)(Hhi + (size_t)s3 * HID + sub * 8);
                    u8v v4 = *(const u8v*)(Hhi + (size_t)s4 * HID + sub * 8);
                    u8v v5 = *(const u8v*)(Hhi + (size_t)s5 * HID + sub * 8);
                    u8v v6 = *(const u8v*)(Hhi + (size_t)s6 * HID + sub * 8);
                    u8v v7 = *(const u8v*)(Hhi + (size_t)s7 * HID + sub * 8);
                    #pragma unroll
                    for (int j = 0; j < 8; ++j)
                        a[j] += ((bf2f(v0[j]) + bf2f(v1[j])) + (bf2f(v2[j]) + bf2f(v3[j])))
                              + ((bf2f(v4[j]) + bf2f(v5[j])) + (bf2f(v6[j]) + bf2f(v7[j])));
                }
                if (p + 4 <= end) {
                    int s0 = csr[p], s1 = csr[p + 1], s2 = csr[p + 2], s3 = csr[p + 3];
                    u8v v0 = *(const u8v*)(Hhi + (size_t)s0 * HID + sub * 8);
                    u8v v1 = *(const u8v*)(Hhi + (size_t)s1 * HID + sub * 8);
                    u8v v2 = *(const u8v*)(Hhi + (size_t)s2 * HID + sub * 8);
                    u8v v3 = *(const u8v*)(Hhi + (size_t)s3 * HID + sub * 8);
                    #pragma unroll
                    for (int j = 0; j < 8; ++j)
                        a[j] += (bf2f(v0[j]) + bf2f(v1[j])) + (bf2f(v2[j]) + bf2f(v3[j]));
                    p += 4;
                }
                for (; p < end; ++p) {
                    int s = csr[p];
                    u8v v = *(const u8v*)(Hhi + (size_t)s * HID + sub * 8);
                    #pragma unroll
                    for (int j = 0; j < 8; ++j) a[j] += bf2f(v[j]);
                }
            }
            u8v hh, ll;
            #pragma unroll
            for (int j = 0; j < 8; ++j) {
                unsigned short hj, lj;
                split_bf(a[j] * inv, hj, lj);
                hh[j] = hj; ll[j] = lj;
            }
            *(u8v*)(&MhS[nloc * 136 + sub * 8]) = hh;
            *(u8v*)(&MlS[nloc * 136 + sub * 8]) = ll;
        }
    }

    // ---------- Phase B: GEMM ----------
    const int wave = tid >> 6, lane = tid & 63;
    const int mIdx = lane & 15, q = lane >> 4;
    const int wrow = (wave & 1) * 32, wcol = (wave >> 1) * 64;

    size_t aoff[2];
    #pragma unroll
    for (int t = 0; t < 2; ++t) {
        int node = rb + wrow + t * 16 + mIdx;
        if (node > N_NODES - 1) node = N_NODES - 1;   // clamp; store is guarded
        aoff[t] = (size_t)node * HID + q * 8;
    }
    const int bcol = tid & 127;
    const int bseg = (tid >> 7) * 16;

    f4v acc[2][4];
    #pragma unroll
    for (int a = 0; a < 2; ++a)
        #pragma unroll
        for (int b = 0; b < 4; ++b) acc[a][b] = (f4v){0.f, 0.f, 0.f, 0.f};

    s8v pAh[2][2], pAl[2][2];   // phase-1 A register prefetch

    #pragma unroll 1
    for (int p = 0; p < 8; ++p) {        // 8 panels of k=32; p<4: Wl/mean, else Wr/h
        const int ph = p >> 2;
        const int kb = (p & 3) * 32;
        const unsigned short* Wh_ = Whi + ph * HID * HID;
        const unsigned short* Wl_ = Wlo + ph * HID * HID;
        __syncthreads();                 // prev panel's B reads done (also covers MhS after phase A)
        *(s8v*)(&BhS[bcol * 40 + bseg])     = *(const s8v*)(Wh_ + bcol * HID + kb + bseg);
        *(s8v*)(&BhS[bcol * 40 + bseg + 8]) = *(const s8v*)(Wh_ + bcol * HID + kb + bseg + 8);
        *(s8v*)(&BlS[bcol * 40 + bseg])     = *(const s8v*)(Wl_ + bcol * HID + kb + bseg);
        *(s8v*)(&BlS[bcol * 40 + bseg + 8]) = *(const s8v*)(Wl_ + bcol * HID + kb + bseg + 8);
        __syncthreads();
        if (p + 1 >= 4 && p + 1 < 8) {   // prefetch next panel's global A frags
            const int kc = ((p + 1) & 3) * 32;
            const int buf = (p + 1) & 1;
            #pragma unroll
            for (int t = 0; t < 2; ++t) {
                pAh[buf][t] = *(const s8v*)(Hhi + aoff[t] + kc);
                pAl[buf][t] = *(const s8v*)(Hlo + aoff[t] + kc);
            }
        }
        s8v Ah_f[2], Al_f[2];
        if (p < 4) {
            #pragma unroll
            for (int t = 0; t < 2; ++t) {
                const int r = wrow + t * 16 + mIdx;
                Ah_f[t] = *(const s8v*)(&MhS[r * 136 + kb + q * 8]);
                Al_f[t] = *(const s8v*)(&MlS[r * 136 + kb + q * 8]);
            }
        } else {
            const int buf = p & 1;
            #pragma unroll
            for (int t = 0; t < 2; ++t) { Ah_f[t] = pAh[buf][t]; Al_f[t] = pAl[buf][t]; }
        }
        s8v Bh_f[4], Bl_f[4];
        #pragma unroll
        for (int nt = 0; nt < 4; ++nt) {
            const int a = (wcol + nt * 16 + mIdx) * 40 + q * 8;
            Bh_f[nt] = *(const s8v*)(&BhS[a]);
            Bl_f[nt] = *(const s8v*)(&BlS[a]);
        }
        #pragma unroll
        for (int mt = 0; mt < 2; ++mt)
            #pragma unroll
            for (int nt = 0; nt < 4; ++nt) {
                acc[mt][nt] = __builtin_amdgcn_mfma_f32_16x16x32_bf16(
                    Ah_f[mt], Bh_f[nt], acc[mt][nt], 0, 0, 0);
                acc[mt][nt] = __builtin_amdgcn_mfma_f32_16x16x32_bf16(
                    Al_f[mt], Bh_f[nt], acc[mt][nt], 0, 0, 0);
                acc[mt][nt] = __builtin_amdgcn_mfma_f32_16x16x32_bf16(
                    Ah_f[mt], Bl_f[nt], acc[mt][nt], 0, 0, 0);
            }
    }

    float bv[4];
    #pragma unroll
    for (int nt = 0; nt < 4; ++nt) bv[nt] = bias[wcol + nt * 16 + mIdx];

    #pragma unroll
    for (int mt = 0; mt < 2; ++mt)
        #pragma unroll
        for (int r = 0; r < 4; ++r) {
            int node = rb + wrow + mt * 16 + q * 4 + r;
            if (node < N_NODES) {
                #pragma unroll
                for (int nt = 0; nt < 4; ++nt) {
                    int feat = wcol + nt * 16 + mIdx;
                    float v = acc[mt][nt][r] + bv[nt];
                    if (RELU) v = fmaxf(v, 0.f);
                    size_t oidx = (size_t)node * HID + feat;
                    if (FINAL) {
                        of32[oidx] = v;
                    } else {
                        unsigned short hh, ll;
                        split_bf(v, hh, ll);
                        ohi[oidx] = hh;
                        olo[oidx] = ll;
                    }
                }
            }
        }
}

// ---------------- launch ----------------
extern "C" void kernel_launch(void* const* d_in, const int* in_sizes, int n_in,
                              void* d_out, int out_size, void* d_ws, size_t ws_size,
                              hipStream_t stream) {
    const float* x   = (const float*)d_in[0];
    const void* edges = d_in[1];
    const float* Wl1 = (const float*)d_in[2];
    const float* Wr1 = (const float*)d_in[3];
    const float* b1  = (const float*)d_in[4];
    const float* Wl2 = (const float*)d_in[5];
    const float* Wr2 = (const float*)d_in[6];
    const float* b2  = (const float*)d_in[7];
    const float* Wl3 = (const float*)d_in[8];
    const float* Wr3 = (const float*)d_in[9];
    const float* b3  = (const float*)d_in[10];
    float* out = (float*)d_out;

    char* ws = (char*)d_ws;
    size_t off = 0;
    auto alloc = [&](size_t bytes) -> void* {
        void* p = (void*)(ws + off);
        off += (bytes + 255) & ~(size_t)255;
        return p;
    };
    typedef unsigned short u16;
    const size_t FEAT = (size_t)N_NODES * HID;
    int* flag     = (int*)alloc(256);
    int* deg      = (int*)alloc((size_t)N_NODES * 4);
    int* offs     = (int*)alloc((size_t)(N_NODES + 1) * 4);
    int* cursor   = (int*)alloc((size_t)N_NODES * 4);
    int* blocksum = (int*)alloc(256 * 4);
    int* csr      = (int*)alloc((size_t)N_EDGES * 4);
    u16* whi      = (u16*)alloc((size_t)6 * HID * HID * 2);
    u16* wlo      = (u16*)alloc((size_t)6 * HID * HID * 2);
    u16* xhi      = (u16*)alloc(FEAT * 2);   // reused as h2_hi
    u16* xlo      = (u16*)alloc(FEAT * 2);   // reused as h2_lo
    u16* h1hi     = (u16*)alloc(FEAT * 2);
    u16* h1lo     = (u16*)alloc(FEAT * 2);
    (void)ws_size; (void)in_sizes; (void)n_in; (void)out_size;

    const int EB = (N_EDGES + 255) / 256;       // 2344
    const int NB = (N_NODES + 255) / 256;       // 196
    const int LYR_B = (N_NODES + 63) / 64;      // 782
    const int PREP_B = ((int)(FEAT / 4) + 255) / 256;    // 6250

    hipMemsetAsync(deg, 0, (size_t)N_NODES * 4, stream);
    detect_mode<<<1, 1024, 0, stream>>>(edges, flag);
    count_deg<<<EB, 256, 0, stream>>>(edges, flag, deg);
    scan_block<<<NB, 256, 0, stream>>>(deg, offs, blocksum);
    scan_top<<<1, 256, 0, stream>>>(blocksum, NB);
    scan_add<<<NB, 256, 0, stream>>>(offs, cursor, blocksum, NB);
    fill_csr<<<EB, 256, 0, stream>>>(edges, flag, cursor, csr);
    prep<<<PREP_B, 256, 0, stream>>>(Wl1, Wr1, Wl2, Wr2, Wl3, Wr3, whi, wlo,
                                     x, xhi, xlo, (int)(FEAT / 4));

    // Layer 1: relu(sage(x)) -> h1 (hi/lo)
    sage_layer<1, 0><<<LYR_B, 256, 0, stream>>>(xhi, xlo, offs, csr,
        whi, wlo, b1, h1hi, h1lo, (float*)nullptr);
    // Layer 2 -> h2 (reuses x buffers)
    sage_layer<0, 0><<<LYR_B, 256, 0, stream>>>(h1hi, h1lo, offs, csr,
        whi + 2 * HID * HID, wlo + 2 * HID * HID, b2, xhi, xlo, (float*)nullptr);
    // Layer 3 -> fp32 out
    sage_layer<0, 1><<<LYR_B, 256, 0, stream>>>(xhi, xlo, offs, csr,
        whi + 4 * HID * HID, wlo + 4 * HID * HID, b3,
        (u16*)nullptr, (u16*)nullptr, out);
}

// Round 7
// 356.148 us; speedup vs baseline: 1.7055x; 1.7055x over previous
//
#include <hip/hip_runtime.h>
#include <hip/hip_bf16.h>

#define N_NODES 50000
#define N_EDGES 600000
#define HID 128

typedef __attribute__((ext_vector_type(8))) short s8v;            // 8 bf16 = 4 VGPR
typedef __attribute__((ext_vector_type(8))) unsigned short u8v;   // 8 ushort
typedef __attribute__((ext_vector_type(4))) float f4v;            // MFMA acc

// ---------------- bf16 helpers ----------------
__device__ __forceinline__ unsigned short f2bf(float x) {
    unsigned u = __float_as_uint(x);
    unsigned r = u + 0x7FFFu + ((u >> 16) & 1u);   // RNE
    return (unsigned short)(r >> 16);
}
__device__ __forceinline__ float bf2f(unsigned short u) {
    return __uint_as_float((unsigned)u << 16);
}
__device__ __forceinline__ void split_bf(float x, unsigned short& hi, unsigned short& lo) {
    hi = f2bf(x);
    lo = f2bf(x - bf2f(hi));
}

// ---------------- inline edge-dtype detection (per block) ----------------
// int64 edges: odd int32 words of the first 256 entries are high words of
// values < 50000 -> all zero. int32 edges: they are random src values.
__device__ __forceinline__ int detect_m64_block(const void* edges) {
    __shared__ int m64s;
    if (threadIdx.x == 0) m64s = 1;
    __syncthreads();
    const int* p = (const int*)edges;
    if (p[2 * threadIdx.x + 1] != 0) m64s = 0;   // benign race, all write 0
    __syncthreads();
    return m64s;
}

__device__ __forceinline__ int edge_at(const void* edges, int mode64, long long idx) {
    return mode64 ? (int)((const long long*)edges)[idx] : ((const int*)edges)[idx];
}

// ---------------- CSR build ----------------
__global__ void count_deg(const void* __restrict__ edges, int* __restrict__ deg) {
    int m = detect_m64_block(edges);
    int e = blockIdx.x * 256 + threadIdx.x;
    if (e >= N_EDGES) return;
    int d = edge_at(edges, m, (long long)N_EDGES + e);
    if ((unsigned)d < (unsigned)N_NODES) atomicAdd(&deg[d], 1);
}

__global__ void scan_block(const int* __restrict__ deg, int* __restrict__ offs,
                           int* __restrict__ blocksum) {
    __shared__ int sm[256];
    int i = blockIdx.x * 256 + threadIdx.x;
    int v = (i < N_NODES) ? deg[i] : 0;
    sm[threadIdx.x] = v;
    __syncthreads();
    #pragma unroll
    for (int s = 1; s < 256; s <<= 1) {
        int t = (threadIdx.x >= (unsigned)s) ? sm[threadIdx.x - s] : 0;
        __syncthreads();
        sm[threadIdx.x] += t;
        __syncthreads();
    }
    if (i < N_NODES) offs[i] = sm[threadIdx.x] - v;   // exclusive within block
    if (threadIdx.x == 255) blocksum[blockIdx.x] = sm[255];
}

// scan_top merged in: every block redundantly scans the 196 block sums in LDS.
__global__ void scan_add(int* __restrict__ offs, int* __restrict__ cursor,
                         const int* __restrict__ blocksum, int nblocks) {
    __shared__ int sm[256];
    int v = ((int)threadIdx.x < nblocks) ? blocksum[threadIdx.x] : 0;
    sm[threadIdx.x] = v;
    __syncthreads();
    #pragma unroll
    for (int s = 1; s < 256; s <<= 1) {
        int t = (threadIdx.x >= (unsigned)s) ? sm[threadIdx.x - s] : 0;
        __syncthreads();
        sm[threadIdx.x] += t;
        __syncthreads();
    }
    const int pre = (blockIdx.x == 0) ? 0 : sm[blockIdx.x - 1];
    const int total = sm[nblocks - 1];
    int i = blockIdx.x * 256 + threadIdx.x;
    if (i < N_NODES) {
        int o = offs[i] + pre;
        offs[i] = o;
        cursor[i] = o;
    }
    if (i == 0) offs[N_NODES] = total;
}

__global__ void fill_csr(const void* __restrict__ edges, int* __restrict__ cursor,
                         int* __restrict__ csr) {
    int m = detect_m64_block(edges);
    int e = blockIdx.x * 256 + threadIdx.x;
    if (e >= N_EDGES) return;
    int d = edge_at(edges, m, (long long)N_EDGES + e);
    int s = edge_at(edges, m, (long long)e);
    if ((unsigned)d >= (unsigned)N_NODES || (unsigned)s >= (unsigned)N_NODES) return;
    int pos = atomicAdd(&cursor[d], 1);
    csr[pos] = s;
}

// ---------------- prep: weight split + x split (merged) ----------------
__global__ void prep(const float* __restrict__ m0, const float* __restrict__ m1,
                     const float* __restrict__ m2, const float* __restrict__ m3,
                     const float* __restrict__ m4, const float* __restrict__ m5,
                     unsigned short* __restrict__ whi, unsigned short* __restrict__ wlo,
                     const float* __restrict__ x, unsigned short* __restrict__ xhi,
                     unsigned short* __restrict__ xlo, int n4) {
    int i = blockIdx.x * 256 + threadIdx.x;
    if (i < 6 * HID * HID) {
        int mat = i >> 14, off = i & 16383;
        const float* src = mat == 0 ? m0 : mat == 1 ? m1 : mat == 2 ? m2
                         : mat == 3 ? m3 : mat == 4 ? m4 : m5;
        unsigned short h, l;
        split_bf(src[off], h, l);
        whi[i] = h; wlo[i] = l;
    }
    if (i < n4) {
        float4 v = ((const float4*)x)[i];
        ushort4 h, l;
        split_bf(v.x, h.x, l.x);
        split_bf(v.y, h.y, l.y);
        split_bf(v.z, h.z, l.z);
        split_bf(v.w, h.w, l.w);
        ((ushort4*)xhi)[i] = h;
        ((ushort4*)xlo)[i] = l;
    }
}

// ---------------- mean aggregation (bf16-hi gather, hi-only output) ---------
// 16 lanes per node, one u8v (16B) per lane covers the 256B row.
// 8-way unrolled gather -> 32 outstanding loads per wave (latency-bound:
// MLP is the lever). mean-lo is NOT produced: its GEMM contribution is
// rms ~1.6e-4, negligible vs the 0.0078 absmax from the hi-only gather.
__global__ __launch_bounds__(256) void aggregate_bf16(const unsigned short* __restrict__ h,
                                                      const int* __restrict__ offs,
                                                      const int* __restrict__ csr,
                                                      unsigned short* __restrict__ mhi) {
    const int sub  = threadIdx.x & 15;
    const int node = blockIdx.x * 16 + (threadIdx.x >> 4);
    if (node >= N_NODES) return;
    const int beg = offs[node], end = offs[node + 1];
    float a[8] = {0.f, 0.f, 0.f, 0.f, 0.f, 0.f, 0.f, 0.f};
    int p = beg;
    for (; p + 8 <= end; p += 8) {
        int s0 = csr[p],     s1 = csr[p + 1], s2 = csr[p + 2], s3 = csr[p + 3];
        int s4 = csr[p + 4], s5 = csr[p + 5], s6 = csr[p + 6], s7 = csr[p + 7];
        u8v v0 = *(const u8v*)(h + (size_t)s0 * HID + sub * 8);
        u8v v1 = *(const u8v*)(h + (size_t)s1 * HID + sub * 8);
        u8v v2 = *(const u8v*)(h + (size_t)s2 * HID + sub * 8);
        u8v v3 = *(const u8v*)(h + (size_t)s3 * HID + sub * 8);
        u8v v4 = *(const u8v*)(h + (size_t)s4 * HID + sub * 8);
        u8v v5 = *(const u8v*)(h + (size_t)s5 * HID + sub * 8);
        u8v v6 = *(const u8v*)(h + (size_t)s6 * HID + sub * 8);
        u8v v7 = *(const u8v*)(h + (size_t)s7 * HID + sub * 8);
        #pragma unroll
        for (int j = 0; j < 8; ++j)
            a[j] += ((bf2f(v0[j]) + bf2f(v1[j])) + (bf2f(v2[j]) + bf2f(v3[j])))
                  + ((bf2f(v4[j]) + bf2f(v5[j])) + (bf2f(v6[j]) + bf2f(v7[j])));
    }
    if (p + 4 <= end) {
        int s0 = csr[p], s1 = csr[p + 1], s2 = csr[p + 2], s3 = csr[p + 3];
        u8v v0 = *(const u8v*)(h + (size_t)s0 * HID + sub * 8);
        u8v v1 = *(const u8v*)(h + (size_t)s1 * HID + sub * 8);
        u8v v2 = *(const u8v*)(h + (size_t)s2 * HID + sub * 8);
        u8v v3 = *(const u8v*)(h + (size_t)s3 * HID + sub * 8);
        #pragma unroll
        for (int j = 0; j < 8; ++j)
            a[j] += (bf2f(v0[j]) + bf2f(v1[j])) + (bf2f(v2[j]) + bf2f(v3[j]));
        p += 4;
    }
    for (; p < end; ++p) {
        int s = csr[p];
        u8v v = *(const u8v*)(h + (size_t)s * HID + sub * 8);
        #pragma unroll
        for (int j = 0; j < 8; ++j) a[j] += bf2f(v[j]);
    }
    const float inv = 1.0f / fmaxf((float)(end - beg), 1.0f);
    u8v hh;
    #pragma unroll
    for (int j = 0; j < 8; ++j) hh[j] = f2bf(a[j] * inv);
    *(u8v*)(mhi + (size_t)node * HID + sub * 8) = hh;
}

// ---------------- MFMA SAGE GEMM (split-bf16) ----------------
// out[i,:] = mean[i,:] @ Wl^T + h[i,:] @ Wr^T + b  via 16x16x32 bf16 MFMA.
// Mean phase: 2 terms (Mh*Bh + Mh*Bl); self phase: 3 terms (+ Hl*Bh).
// Block 256 thr = 4 waves; tile 128x128; wave -> 64x64 quadrant (4x4 tiles).
// B staged in LDS per 64-k panel (stride 72 shorts: 2-way banks = free).
// A register-direct, 2-deep double buffered.
template <int RELU, int FINAL>
__global__ __launch_bounds__(256) void sage_mfma(
    const unsigned short* __restrict__ Mhi,
    const unsigned short* __restrict__ Hhi, const unsigned short* __restrict__ Hlo,
    const unsigned short* __restrict__ Whi, const unsigned short* __restrict__ Wlo,
    const float* __restrict__ bias,
    unsigned short* __restrict__ ohi, unsigned short* __restrict__ olo,
    float* __restrict__ of32) {
    __shared__ short BhS[128 * 72];   // [col][k-in-panel], stride 72
    __shared__ short BlS[128 * 72];
    const int tid = threadIdx.x;
    const int wave = tid >> 6, lane = tid & 63;
    const int mIdx = lane & 15, q = lane >> 4;
    const int wrow = (wave & 1) * 64, wcol = (wave >> 1) * 64;
    const int rowBase = blockIdx.x * 128;

    size_t aoff[4];
    #pragma unroll
    for (int t = 0; t < 4; ++t) {
        int node = rowBase + wrow + t * 16 + mIdx;
        if (node > N_NODES - 1) node = N_NODES - 1;   // clamp; store is guarded
        aoff[t] = (size_t)node * HID + q * 8;
    }
    const int bcol = tid & 127;
    const int bseg = (tid >> 7) * 32;

    f4v acc[4][4];
    #pragma unroll
    for (int a = 0; a < 4; ++a)
        #pragma unroll
        for (int b = 0; b < 4; ++b) acc[a][b] = (f4v){0.f, 0.f, 0.f, 0.f};

    s8v Ah[2][4], Al[2][4];
    auto loadA = [&](int i, int buf) {         // i = global chunk 0..7
        const int kc = (i & 3) * 32;
        if (i < 4) {
            #pragma unroll
            for (int t = 0; t < 4; ++t)
                Ah[buf][t] = *(const s8v*)(Mhi + aoff[t] + kc);
        } else {
            #pragma unroll
            for (int t = 0; t < 4; ++t) {
                Ah[buf][t] = *(const s8v*)(Hhi + aoff[t] + kc);
                Al[buf][t] = *(const s8v*)(Hlo + aoff[t] + kc);
            }
        }
    };

    loadA(0, 0);
    #pragma unroll 1
    for (int panel = 0; panel < 4; ++panel) {  // 64-k panel
        const int ph = panel >> 1;             // 0: Wl/mean, 1: Wr/self
        const int kb = (panel & 1) * 64;
        const unsigned short* Wh_ = Whi + ph * HID * HID;
        const unsigned short* Wl_ = Wlo + ph * HID * HID;
        __syncthreads();                        // prev panel's LDS reads done
        {
            const unsigned short* sh = Wh_ + bcol * HID + kb + bseg;
            const unsigned short* sl = Wl_ + bcol * HID + kb + bseg;
            short* dh = BhS + bcol * 72 + bseg;
            short* dl = BlS + bcol * 72 + bseg;
            #pragma unroll
            for (int j = 0; j < 4; ++j) {
                *(s8v*)(dh + j * 8) = *(const s8v*)(sh + j * 8);
                *(s8v*)(dl + j * 8) = *(const s8v*)(sl + j * 8);
            }
        }
        __syncthreads();
        #pragma unroll
        for (int c = 0; c < 2; ++c) {          // two k=32 chunks per panel
            const int i = panel * 2 + c;
            if (i < 7) loadA(i + 1, (i + 1) & 1);
            const int kc2 = c * 32;
            s8v Bh_f[4], Bl_f[4];
            #pragma unroll
            for (int nt = 0; nt < 4; ++nt) {
                const int a = (wcol + nt * 16 + mIdx) * 72 + kc2 + q * 8;
                Bh_f[nt] = *(const s8v*)(BhS + a);
                Bl_f[nt] = *(const s8v*)(BlS + a);
            }
            const int buf = i & 1;
            if (panel < 2) {                   // mean phase: 2 terms
                #pragma unroll
                for (int mt = 0; mt < 4; ++mt)
                    #pragma unroll
                    for (int nt = 0; nt < 4; ++nt) {
                        acc[mt][nt] = __builtin_amdgcn_mfma_f32_16x16x32_bf16(
                            Ah[buf][mt], Bh_f[nt], acc[mt][nt], 0, 0, 0);
                        acc[mt][nt] = __builtin_amdgcn_mfma_f32_16x16x32_bf16(
                            Ah[buf][mt], Bl_f[nt], acc[mt][nt], 0, 0, 0);
                    }
            } else {                           // self phase: 3 terms
                #pragma unroll
                for (int mt = 0; mt < 4; ++mt)
                    #pragma unroll
                    for (int nt = 0; nt < 4; ++nt) {
                        acc[mt][nt] = __builtin_amdgcn_mfma_f32_16x16x32_bf16(
                            Ah[buf][mt], Bh_f[nt], acc[mt][nt], 0, 0, 0);
                        acc[mt][nt] = __builtin_amdgcn_mfma_f32_16x16x32_bf16(
                            Al[buf][mt], Bh_f[nt], acc[mt][nt], 0, 0, 0);
                        acc[mt][nt] = __builtin_amdgcn_mfma_f32_16x16x32_bf16(
                            Ah[buf][mt], Bl_f[nt], acc[mt][nt], 0, 0, 0);
                    }
            }
        }
    }

    float bv[4];
    #pragma unroll
    for (int nt = 0; nt < 4; ++nt) bv[nt] = bias[wcol + nt * 16 + mIdx];

    #pragma unroll
    for (int mt = 0; mt < 4; ++mt)
        #pragma unroll
        for (int r = 0; r < 4; ++r) {
            int node = rowBase + wrow + mt * 16 + q * 4 + r;
            if (node < N_NODES) {
                #pragma unroll
                for (int nt = 0; nt < 4; ++nt) {
                    int feat = wcol + nt * 16 + mIdx;
                    float v = acc[mt][nt][r] + bv[nt];
                    if (RELU) v = fmaxf(v, 0.f);
                    size_t oidx = (size_t)node * HID + feat;
                    if (FINAL) {
                        of32[oidx] = v;
                    } else {
                        unsigned short hh, ll;
                        split_bf(v, hh, ll);
                        ohi[oidx] = hh;
                        olo[oidx] = ll;
                    }
                }
            }
        }
}

// ---------------- launch ----------------
extern "C" void kernel_launch(void* const* d_in, const int* in_sizes, int n_in,
                              void* d_out, int out_size, void* d_ws, size_t ws_size,
                              hipStream_t stream) {
    const float* x   = (const float*)d_in[0];
    const void* edges = d_in[1];
    const float* Wl1 = (const float*)d_in[2];
    const float* Wr1 = (const float*)d_in[3];
    const float* b1  = (const float*)d_in[4];
    const float* Wl2 = (const float*)d_in[5];
    const float* Wr2 = (const float*)d_in[6];
    const float* b2  = (const float*)d_in[7];
    const float* Wl3 = (const float*)d_in[8];
    const float* Wr3 = (const float*)d_in[9];
    const float* b3  = (const float*)d_in[10];
    float* out = (float*)d_out;

    char* ws = (char*)d_ws;
    size_t off = 0;
    auto alloc = [&](size_t bytes) -> void* {
        void* p = (void*)(ws + off);
        off += (bytes + 255) & ~(size_t)255;
        return p;
    };
    typedef unsigned short u16;
    const size_t FEAT = (size_t)N_NODES * HID;
    int* deg      = (int*)alloc((size_t)N_NODES * 4);
    int* offs     = (int*)alloc((size_t)(N_NODES + 1) * 4);
    int* cursor   = (int*)alloc((size_t)N_NODES * 4);
    int* blocksum = (int*)alloc(256 * 4);
    int* csr      = (int*)alloc((size_t)N_EDGES * 4);
    u16* whi      = (u16*)alloc((size_t)6 * HID * HID * 2);
    u16* wlo      = (u16*)alloc((size_t)6 * HID * HID * 2);
    u16* xhi      = (u16*)alloc(FEAT * 2);   // reused as h2_hi
    u16* xlo      = (u16*)alloc(FEAT * 2);   // reused as h2_lo
    u16* h1hi     = (u16*)alloc(FEAT * 2);
    u16* h1lo     = (u16*)alloc(FEAT * 2);
    u16* mhi      = (u16*)alloc(FEAT * 2);
    (void)ws_size; (void)in_sizes; (void)n_in; (void)out_size;

    const int EB = (N_EDGES + 255) / 256;       // 2344
    const int NB = (N_NODES + 255) / 256;       // 196
    const int AGG_B = (N_NODES + 15) / 16;      // 3125
    const int GEMM_B = (N_NODES + 127) / 128;   // 391
    const int PREP_B = ((int)(FEAT / 4) + 255) / 256;    // 6250

    hipMemsetAsync(deg, 0, (size_t)N_NODES * 4, stream);
    count_deg<<<EB, 256, 0, stream>>>(edges, deg);
    scan_block<<<NB, 256, 0, stream>>>(deg, offs, blocksum);
    scan_add<<<NB, 256, 0, stream>>>(offs, cursor, blocksum, NB);
    fill_csr<<<EB, 256, 0, stream>>>(edges, cursor, csr);
    prep<<<PREP_B, 256, 0, stream>>>(Wl1, Wr1, Wl2, Wr2, Wl3, Wr3, whi, wlo,
                                     x, xhi, xlo, (int)(FEAT / 4));

    // Layer 1: relu(sage(x)) -> h1 (hi/lo)
    aggregate_bf16<<<AGG_B, 256, 0, stream>>>(xhi, offs, csr, mhi);
    sage_mfma<1, 0><<<GEMM_B, 256, 0, stream>>>(mhi, xhi, xlo,
        whi, wlo, b1, h1hi, h1lo, (float*)nullptr);
    // Layer 2 -> h2 (reuses x buffers)
    aggregate_bf16<<<AGG_B, 256, 0, stream>>>(h1hi, offs, csr, mhi);
    sage_mfma<0, 0><<<GEMM_B, 256, 0, stream>>>(mhi, h1hi, h1lo,
        whi + 2 * HID * HID, wlo + 2 * HID * HID, b2, xhi, xlo, (float*)nullptr);
    // Layer 3 -> fp32 out
    aggregate_bf16<<<AGG_B, 256, 0, stream>>>(xhi, offs, csr, mhi);
    sage_mfma<0, 1><<<GEMM_B, 256, 0, stream>>>(mhi, xhi, xlo,
        whi + 4 * HID * HID, wlo + 4 * HID * HID, b3,
        (u16*)nullptr, (u16*)nullptr, out);
}